// Round 4
// baseline (534.794 us; speedup 1.0000x reference)
//
#include <hip/hip_runtime.h>
#include <math.h>

// Problem constants (B=16, C=3 -> 48 planes of 512x512)
#define H_IMG 512
#define W_IMG 512
#define TW 32              // strip width (output cols per block)
#define CH 32              // output rows per chunk
#define NCHUNK 4           // chunks per block -> 128 output rows per block
#define STRIP (CH*NCHUNK)  // 128
#define HALO 5
#define WS11 11
#define RING 42            // ring rows: live window is 42 (32 new + 10 reused)
#define RS 36              // row stride in floats (32 cols + pad, 16B-aligned rows)
#define FSTR (RING*RS)     // 1512 floats per field
#define NTHREADS 256

typedef float f2 __attribute__((ext_vector_type(2)));

// Raw barrier: orders LDS (lgkmcnt) across waves WITHOUT draining vmcnt,
// so register-prefetch global loads stay in flight across it.
// (__syncthreads would emit s_waitcnt vmcnt(0) and kill the pipeline.)
#define BAR() do { \
    asm volatile("s_waitcnt lgkmcnt(0)" ::: "memory"); \
    __builtin_amdgcn_s_barrier(); \
} while (0)

// Gaussian 11-tap, sigma=1.5, normalized; folds to literals after unroll.
// Out-of-range taps -> 0 so packed pairs can run harmlessly.
__host__ __device__ constexpr float WT(int t) {
    return (t==0||t==10) ? 0.00102838f :
           (t==1||t==9)  ? 0.00759873f :
           (t==2||t==8)  ? 0.03600075f :
           (t==3||t==7)  ? 0.10936070f :
           (t==4||t==6)  ? 0.21300556f :
           (t==5)        ? 0.26601172f : 0.0f;
}

static __device__ __forceinline__ f2 splat2(float v) { f2 r = {v, v}; return r; }

// Column-strip kernel: block = 32 cols x 128 rows of one plane.
// Hconv rows (5 fields) live in a 42-row LDS ring; each image row is
// hconv'd once per block. Interior blocks prefetch chunk k+1's raw rows
// into NAMED float4 registers right after consuming chunk k; the loads'
// latency hides under Stage B + two raw barriers (T14, spill-safe form).
__global__ __launch_bounds__(NTHREADS, 4) void ssim_mse_tile(
        const float* __restrict__ cover, const float* __restrict__ wmed,
        float* __restrict__ part, int nParts) {
    __shared__ __align__(16) float rbuf[5*FSTR];   // 30240 B

    const int tid = threadIdx.x;
    const int bx  = blockIdx.x & 15;          // x-strip
    const int ys  = (blockIdx.x >> 4) & 3;    // y quarter
    const int pl  = blockIdx.x >> 6;          // plane
    const size_t pbase = (size_t)pl * (H_IMG*W_IMG);
    const float* xp = wmed + pbase;           // x = wmed, y = cover
    const float* yp = cover + pbase;
    const int Y0  = ys << 7;                  // 0,128,256,384
    const int tx0 = bx*TW - HALO;
    const bool xin = (bx != 0) && (bx != 15); // fast-path columns

    const int rA  = tid >> 3;                 // steady task row 0..31
    const int c0  = (tid & 7) << 2;           // task col group
    const int cB  = tid & 31;                 // Stage B column
    const int rgB = tid >> 5;                 // Stage B row group 0..7

    float ssim_acc = 0.f, mse_acc = 0.f;
    // Prefetch registers: individually named (no struct -> no SROA hazard).
    float4 pXA, pXB, pXC, pXD, pYA, pYB, pYC, pYD;
    float  pXE, pYE;

    // ---- Prologue: chunk 0 (42 rows = 336 tasks), direct loads ----
    for (int t = tid; t < 336; t += NTHREADS) {
        const int r  = t >> 3, cc = (t & 7) << 2;
        const int hr = r - HALO;                 // -5..36
        const int gy = Y0 + hr;
        const bool rok = (unsigned)gy < (unsigned)H_IMG;
        float xv[14], yv[14];
        if (rok && xin) {
            const float* rx = xp + (size_t)gy*W_IMG + (tx0 + cc - 3);
            const float* ry = yp + (size_t)gy*W_IMG + (tx0 + cc - 3);
            float4 XA = *(const float4*)(rx);
            float4 XB = *(const float4*)(rx + 4);
            float4 XC = *(const float4*)(rx + 8);
            float4 XD = *(const float4*)(rx + 12);
            float  XE = rx[16];
            float4 YA = *(const float4*)(ry);
            float4 YB = *(const float4*)(ry + 4);
            float4 YC = *(const float4*)(ry + 8);
            float4 YD = *(const float4*)(ry + 12);
            float  YE = ry[16];
            xv[0]=XA.w;  xv[1]=XB.x;  xv[2]=XB.y;  xv[3]=XB.z;  xv[4]=XB.w;
            xv[5]=XC.x;  xv[6]=XC.y;  xv[7]=XC.z;  xv[8]=XC.w;  xv[9]=XD.x;
            xv[10]=XD.y; xv[11]=XD.z; xv[12]=XD.w; xv[13]=XE;
            yv[0]=YA.w;  yv[1]=YB.x;  yv[2]=YB.y;  yv[3]=YB.z;  yv[4]=YB.w;
            yv[5]=YC.x;  yv[6]=YC.y;  yv[7]=YC.z;  yv[8]=YC.w;  yv[9]=YD.x;
            yv[10]=YD.y; yv[11]=YD.z; yv[12]=YD.w; yv[13]=YE;
        } else if (rok) {
            const int gc = tx0 + cc;
            const float* prx = xp + (size_t)gy*W_IMG + gc;
            const float* pry = yp + (size_t)gy*W_IMG + gc;
#pragma unroll
            for (int j = 0; j < 14; ++j) {
                bool ok = (unsigned)(gc + j) < (unsigned)W_IMG;
                xv[j] = ok ? prx[j] : 0.f;
                yv[j] = ok ? pry[j] : 0.f;
            }
        } else {
#pragma unroll
            for (int j = 0; j < 14; ++j) { xv[j] = 0.f; yv[j] = 0.f; }
        }
        if ((unsigned)hr < (unsigned)STRIP) {
#pragma unroll
            for (int j = 5; j < 9; ++j) {
                float d = xv[j] - yv[j];
                mse_acc = fmaf(d, d, mse_acc);
            }
        }
        f2 A[5][2];
#pragma unroll
        for (int f = 0; f < 5; ++f) { A[f][0] = splat2(0.f); A[f][1] = splat2(0.f); }
#pragma unroll
        for (int j = 0; j < 14; ++j) {
            float px = xv[j], py = yv[j];
            float pxx = px*px, pyy = py*py, pxy = px*py;
#pragma unroll
            for (int p = 0; p < 2; ++p) {
                const int t0 = j - 2*p;
                if (t0 >= 0 && t0 <= WS11) {
                    const f2 wp = {WT(t0), WT(t0-1)};
                    A[0][p] = __builtin_elementwise_fma(wp, splat2(px),  A[0][p]);
                    A[1][p] = __builtin_elementwise_fma(wp, splat2(py),  A[1][p]);
                    A[2][p] = __builtin_elementwise_fma(wp, splat2(pxx), A[2][p]);
                    A[3][p] = __builtin_elementwise_fma(wp, splat2(pyy), A[3][p]);
                    A[4][p] = __builtin_elementwise_fma(wp, splat2(pxy), A[4][p]);
                }
            }
        }
        float* wb = &rbuf[r*RS + cc];           // slot = hr+HALO = r
#pragma unroll
        for (int f = 0; f < 5; ++f) {
            *(float4*)(wb + f*FSTR) =
                make_float4(A[f][0].x, A[f][0].y, A[f][1].x, A[f][1].y);
        }
    }
    // ---- Issue prefetch of chunk 1 (interior blocks; rows always valid) ----
    if (xin) {
        const int gy1 = Y0 + CH + HALO + rA;    // <= 452 < 512
        const float* rx = xp + (size_t)gy1*W_IMG + (tx0 + c0 - 3);
        const float* ry = yp + (size_t)gy1*W_IMG + (tx0 + c0 - 3);
        pXA = *(const float4*)(rx);
        pXB = *(const float4*)(rx + 4);
        pXC = *(const float4*)(rx + 8);
        pXD = *(const float4*)(rx + 12);
        pXE = rx[16];
        pYA = *(const float4*)(ry);
        pYB = *(const float4*)(ry + 4);
        pYC = *(const float4*)(ry + 8);
        pYD = *(const float4*)(ry + 12);
        pYE = ry[16];
    }
    BAR();

    int slotA = rA;                 // ring slot of chunk-1 row (hr+5 mod 42)
    int sbB   = rgB << 2;           // Stage B base slot (chunk 0)

    for (int k = 0; k < NCHUNK; ++k) {
        // ---- Stage B: vertical 11-tap + SSIM; ALL 256 threads.
        //      4 output rows x 1 col; row-pair packed f2 accumulators,
        //      b32 LDS reads (measured conflict-free). ----
        {
            f2 acc[5][2];
#pragma unroll
            for (int f = 0; f < 5; ++f) {
                acc[f][0] = splat2(0.f); acc[f][1] = splat2(0.f);
            }
            const float* bp = rbuf + cB;
#pragma unroll
            for (int i = 0; i < 14; ++i) {
                int sl = sbB + i; if (sl >= RING) sl -= RING;
                const float* rp = bp + sl*RS;
#pragma unroll
                for (int f = 0; f < 5; ++f) {
                    float v = rp[f*FSTR];
#pragma unroll
                    for (int p = 0; p < 2; ++p) {
                        const int t0 = i - 2*p;
                        if (t0 >= 0 && t0 <= WS11) {
                            const f2 wp = {WT(t0), WT(t0-1)};
                            acc[f][p] = __builtin_elementwise_fma(wp, splat2(v), acc[f][p]);
                        }
                    }
                }
            }
            const f2 c1v = {1e-4f, 1e-4f};
            const f2 c2v = {9e-4f, 9e-4f};
            const f2 two2 = {2.f, 2.f};
#pragma unroll
            for (int p = 0; p < 2; ++p) {
                f2 mx = acc[0][p], my = acc[1][p];
                f2 sxx = acc[2][p] - mx*mx;
                f2 syy = acc[3][p] - my*my;
                f2 sxy = acc[4][p] - mx*my;
                f2 num = (two2*mx*my + c1v) * (two2*sxy + c2v);
                f2 den = (mx*mx + my*my + c1v) * (sxx + syy + c2v);
                ssim_acc += __fdividef(num.x, den.x) + __fdividef(num.y, den.y);
            }
        }

        if (k + 1 < NCHUNK) {
            BAR();   // B(k) LDS reads done before A(k+1) overwrites ring
            // ---- Stage A(k+1): consume prefetch, hconv, issue chunk k+2 ----
            const int  hr  = CH*(k+1) + HALO + rA;
            const int  gy  = Y0 + hr;
            const bool rok = gy < H_IMG;         // gy >= 37 always
            float xv[14], yv[14];
            if (xin) {
                xv[0]=pXA.w;  xv[1]=pXB.x;  xv[2]=pXB.y;  xv[3]=pXB.z;  xv[4]=pXB.w;
                xv[5]=pXC.x;  xv[6]=pXC.y;  xv[7]=pXC.z;  xv[8]=pXC.w;  xv[9]=pXD.x;
                xv[10]=pXD.y; xv[11]=pXD.z; xv[12]=pXD.w; xv[13]=pXE;
                yv[0]=pYA.w;  yv[1]=pYB.x;  yv[2]=pYB.y;  yv[3]=pYB.z;  yv[4]=pYB.w;
                yv[5]=pYC.x;  yv[6]=pYC.y;  yv[7]=pYC.z;  yv[8]=pYC.w;  yv[9]=pYD.x;
                yv[10]=pYD.y; yv[11]=pYD.z; yv[12]=pYD.w; yv[13]=pYE;
#pragma unroll
                for (int j = 0; j < 14; ++j) {
                    xv[j] = rok ? xv[j] : 0.f;
                    yv[j] = rok ? yv[j] : 0.f;
                }
            } else if (rok) {
                const int gc = tx0 + c0;
                const float* prx = xp + (size_t)gy*W_IMG + gc;
                const float* pry = yp + (size_t)gy*W_IMG + gc;
#pragma unroll
                for (int j = 0; j < 14; ++j) {
                    bool ok = (unsigned)(gc + j) < (unsigned)W_IMG;
                    xv[j] = ok ? prx[j] : 0.f;
                    yv[j] = ok ? pry[j] : 0.f;
                }
            } else {
#pragma unroll
                for (int j = 0; j < 14; ++j) { xv[j] = 0.f; yv[j] = 0.f; }
            }
            if (hr < STRIP) {                    // owned rows always rok
#pragma unroll
                for (int j = 5; j < 9; ++j) {
                    float d = xv[j] - yv[j];
                    mse_acc = fmaf(d, d, mse_acc);
                }
            }
            f2 A[5][2];
#pragma unroll
            for (int f = 0; f < 5; ++f) { A[f][0] = splat2(0.f); A[f][1] = splat2(0.f); }
#pragma unroll
            for (int j = 0; j < 14; ++j) {
                float px = xv[j], py = yv[j];
                float pxx = px*px, pyy = py*py, pxy = px*py;
#pragma unroll
                for (int p = 0; p < 2; ++p) {
                    const int t0 = j - 2*p;
                    if (t0 >= 0 && t0 <= WS11) {
                        const f2 wp = {WT(t0), WT(t0-1)};
                        A[0][p] = __builtin_elementwise_fma(wp, splat2(px),  A[0][p]);
                        A[1][p] = __builtin_elementwise_fma(wp, splat2(py),  A[1][p]);
                        A[2][p] = __builtin_elementwise_fma(wp, splat2(pxx), A[2][p]);
                        A[3][p] = __builtin_elementwise_fma(wp, splat2(pyy), A[3][p]);
                        A[4][p] = __builtin_elementwise_fma(wp, splat2(pxy), A[4][p]);
                    }
                }
            }
            float* wb = &rbuf[slotA*RS + c0];
#pragma unroll
            for (int f = 0; f < 5; ++f) {
                *(float4*)(wb + f*FSTR) =
                    make_float4(A[f][0].x, A[f][0].y, A[f][1].x, A[f][1].y);
            }
            if (k + 2 < NCHUNK && xin) {
                int gy2 = gy + CH;               // row for chunk k+2
                if (gy2 > H_IMG-1) gy2 = H_IMG-1;  // clamp; zeroed at consume
                const float* rx = xp + (size_t)gy2*W_IMG + (tx0 + c0 - 3);
                const float* ry = yp + (size_t)gy2*W_IMG + (tx0 + c0 - 3);
                pXA = *(const float4*)(rx);
                pXB = *(const float4*)(rx + 4);
                pXC = *(const float4*)(rx + 8);
                pXD = *(const float4*)(rx + 12);
                pXE = rx[16];
                pYA = *(const float4*)(ry);
                pYB = *(const float4*)(ry + 4);
                pYC = *(const float4*)(ry + 8);
                pYD = *(const float4*)(ry + 12);
                pYE = ry[16];
            }
            slotA += CH; if (slotA >= RING) slotA -= RING;
            sbB   += CH; if (sbB   >= RING) sbB   -= RING;
            BAR();   // A(k+1) ring writes visible to B(k+1)
        }
    }
    __syncthreads();   // all B(3) LDS reads done before scratch reuse

    // ---- Block reduce (4 waves of 64); reuse rbuf as scratch ----
#pragma unroll
    for (int off = 32; off > 0; off >>= 1) {
        ssim_acc += __shfl_down(ssim_acc, off);
        mse_acc  += __shfl_down(mse_acc, off);
    }
    const int wid = tid >> 6, lane = tid & 63;
    if (lane == 0) { rbuf[wid] = ssim_acc; rbuf[4+wid] = mse_acc; }
    __syncthreads();
    if (tid == 0) {
        part[blockIdx.x] = rbuf[0]+rbuf[1]+rbuf[2]+rbuf[3];
        part[nParts + blockIdx.x] = rbuf[4]+rbuf[5]+rbuf[6]+rbuf[7];
    }
}

// 1024-thread finalize: vectorized partial reduce (double), fast-log BCE,
// curriculum weights.
#define FT 1024
__global__ __launch_bounds__(FT) void finalize_k(
        const float* __restrict__ part, int nParts,
        const float* __restrict__ wm_orig, const float* __restrict__ wm_ext,
        int nWm, const int* __restrict__ epoch_p,
        float* __restrict__ out, double inv_npix, double inv_nwm) {
    __shared__ double red[48];
    int tid = threadIdx.x;
    double s_ssim = 0.0, s_mse = 0.0, s_wl = 0.0;
    const float4* s4 = (const float4*)part;
    const float4* m4 = (const float4*)(part + nParts);
    int n4 = nParts >> 2;
    for (int i = tid; i < n4; i += FT) {
        float4 v = s4[i];
        s_ssim += (double)((v.x + v.y) + (v.z + v.w));
        float4 u = m4[i];
        s_mse  += (double)((u.x + u.y) + (u.z + u.w));
    }
    const float4* p4 = (const float4*)wm_orig;
    const float4* q4 = (const float4*)wm_ext;
    int w4 = nWm >> 2;
    for (int i = tid; i < w4; i += FT) {
        float4 p = p4[i], q = q4[i];
        float a;
        a  = -(p.x*__logf(q.x) + (1.f-p.x)*__logf(1.f-q.x));
        a += -(p.y*__logf(q.y) + (1.f-p.y)*__logf(1.f-q.y));
        a += -(p.z*__logf(q.z) + (1.f-p.z)*__logf(1.f-q.z));
        a += -(p.w*__logf(q.w) + (1.f-p.w)*__logf(1.f-q.w));
        s_wl += (double)a;
    }
#pragma unroll
    for (int off = 32; off > 0; off >>= 1) {
        s_ssim += __shfl_down(s_ssim, off);
        s_mse  += __shfl_down(s_mse, off);
        s_wl   += __shfl_down(s_wl, off);
    }
    int wid = tid >> 6, lane = tid & 63;
    if (lane == 0) { red[wid] = s_ssim; red[16+wid] = s_mse; red[32+wid] = s_wl; }
    __syncthreads();
    if (tid == 0) {
        double ssim_sum = 0.0, mse_sum = 0.0, wl_sum = 0.0;
        for (int i = 0; i < 16; ++i) {
            ssim_sum += red[i]; mse_sum += red[16+i]; wl_sum += red[32+i];
        }
        float sv = (float)(ssim_sum * inv_npix);
        float ml = (float)(mse_sum  * inv_npix);
        float wl = (float)(wl_sum   * inv_nwm);
        int e = *epoch_p;
        float w_img, w_ssim;
        if (e <= 12) {
            w_img = 0.05f; w_ssim = 0.05f;
        } else {
            float progress = fminf(1.0f, (float)(e - 12) / 10.0f);
            w_img  = 0.05f + (0.5f - 0.05f)*progress;
            w_ssim = 0.05f + (0.8f - 0.05f)*progress;
        }
        float sl = 1.0f - sv;
        float total = w_img*ml + w_ssim*sl + 3.0f*wl;
        out[0] = total;
        out[1] = ml;
        out[2] = sv;
        out[3] = wl;
    }
}

extern "C" void kernel_launch(void* const* d_in, const int* in_sizes, int n_in,
                              void* d_out, int out_size, void* d_ws, size_t ws_size,
                              hipStream_t stream) {
    const float* cover   = (const float*)d_in[0];
    const float* wmed    = (const float*)d_in[1];
    const float* wm_orig = (const float*)d_in[2];
    const float* wm_ext  = (const float*)d_in[3];
    const int*   epoch   = (const int*)d_in[4];
    float* out = (float*)d_out;

    int npix   = in_sizes[0];                 // 12,582,912
    int planes = npix / (H_IMG * W_IMG);      // 48
    int nWm    = in_sizes[2];                 // 16,384

    int nBlocks = 16 * 4 * planes;            // 3072 column-strip blocks
    int nParts  = nBlocks;
    float* part = (float*)d_ws;               // 2 * nParts floats (24 KB)

    ssim_mse_tile<<<nBlocks, NTHREADS, 0, stream>>>(cover, wmed, part, nParts);
    finalize_k<<<1, FT, 0, stream>>>(part, nParts, wm_orig, wm_ext, nWm,
                                     epoch, out,
                                     1.0 / (double)npix, 1.0 / (double)nWm);
}

// Round 5
// 181.950 us; speedup vs baseline: 2.9392x; 2.9392x over previous
//
#include <hip/hip_runtime.h>
#include <math.h>

// Problem constants (B=16, C=3 -> 48 planes of 512x512)
#define H_IMG 512
#define W_IMG 512
#define TW 32              // strip width (output cols per block)
#define CH 64              // output rows per chunk
#define NCHUNK 2           // chunks per block -> 128 output rows per block
#define STRIP (CH*NCHUNK)  // 128
#define HALO 5
#define WS11 11
#define RING 74            // ring rows: live window is 74 (64 new + 10 reused)
#define RS 36              // row stride in floats (32 cols + pad, 16B-aligned rows)
#define FSTR (RING*RS)     // 2664 floats per field
#define NTHREADS 256

typedef float f2 __attribute__((ext_vector_type(2)));

// Gaussian 11-tap, sigma=1.5, normalized; folds to literals after unroll.
// Out-of-range taps -> 0 so packed pairs can run harmlessly.
__host__ __device__ constexpr float WT(int t) {
    return (t==0||t==10) ? 0.00102838f :
           (t==1||t==9)  ? 0.00759873f :
           (t==2||t==8)  ? 0.03600075f :
           (t==3||t==7)  ? 0.10936070f :
           (t==4||t==6)  ? 0.21300556f :
           (t==5)        ? 0.26601172f : 0.0f;
}

static __device__ __forceinline__ f2 splat2(float v) { f2 r = {v, v}; return r; }

// Column-strip kernel: block = 32 cols x 128 rows of one plane, TWO
// 64-row chunks. Hconv rows (5 fields) live in a 74-row LDS ring; each
// image row is hconv'd once per block (138/128 = 1.08x). Halving the
// chunk count vs CH=32 halves barrier/latency events, and the 8-row
// Stage B task cuts LDS reads/px from 17.5 to 11.25.
// Stage A: chunk0 592 tasks (2.31/thr), chunk1 512 (2/thr).
// Stage B: 256 tasks/chunk = 1/thr (8 rows x 1 col, row-pair packed f2,
//          scalar b32 LDS reads -> bank-conflict-free, measured 0).
__global__ __launch_bounds__(NTHREADS, 3) void ssim_mse_tile(
        const float* __restrict__ cover, const float* __restrict__ wmed,
        float* __restrict__ part, int nParts) {
    __shared__ __align__(16) float rbuf[5*FSTR];   // 53280 B -> 3 blocks/CU

    const int tid = threadIdx.x;
    const int bx  = blockIdx.x & 15;          // x-strip
    const int ys  = (blockIdx.x >> 4) & 3;    // y quarter
    const int pl  = blockIdx.x >> 6;          // plane
    const size_t pbase = (size_t)pl * (H_IMG*W_IMG);
    const float* xp = wmed + pbase;           // x = wmed, y = cover
    const float* yp = cover + pbase;
    const int Y0  = ys << 7;                  // 0,128,256,384
    const int tx0 = bx*TW - HALO;
    const bool xin = (bx != 0) && (bx != 15); // fast-path columns

    float ssim_acc = 0.f, mse_acc = 0.f;

    for (int k = 0; k < NCHUNK; ++k) {
        // ---- Stage A: hconv the NEW rows of this chunk into the ring ----
        // chunk 0: hr in [-5, 69) (74 rows); chunk 1: hr in [69, 133)
        const int nrows = (k == 0) ? (CH + 2*HALO) : CH;
        const int hr0   = (k == 0) ? -HALO : (CH + HALO);
        const int ntask = nrows << 3;          // 8 col-groups of 4

        for (int t = tid; t < ntask; t += NTHREADS) {
            const int r  = t >> 3, c0 = (t & 7) << 2;
            const int hr = hr0 + r;                  // strip-relative row
            const int gy = Y0 + hr;                  // global row
            const int slot = (hr + HALO) % RING;     // ring slot (>=0)
            const bool rok = (unsigned)gy < (unsigned)H_IMG;
            float xv[14], yv[14];
            if (rok && xin) {
                // ga = bx*32 + c0 - 8 : 16B-aligned, in [24, 484]
                const int ga = tx0 + c0 - 3;
                const float* rx = xp + (size_t)gy*W_IMG + ga;
                const float* ry = yp + (size_t)gy*W_IMG + ga;
                float4 XA = *(const float4*)(rx);
                float4 XB = *(const float4*)(rx + 4);
                float4 XC = *(const float4*)(rx + 8);
                float4 XD = *(const float4*)(rx + 12);
                float  XE = rx[16];
                float4 YA = *(const float4*)(ry);
                float4 YB = *(const float4*)(ry + 4);
                float4 YC = *(const float4*)(ry + 8);
                float4 YD = *(const float4*)(ry + 12);
                float  YE = ry[16];
                xv[0]=XA.w;  xv[1]=XB.x;  xv[2]=XB.y;  xv[3]=XB.z;  xv[4]=XB.w;
                xv[5]=XC.x;  xv[6]=XC.y;  xv[7]=XC.z;  xv[8]=XC.w;  xv[9]=XD.x;
                xv[10]=XD.y; xv[11]=XD.z; xv[12]=XD.w; xv[13]=XE;
                yv[0]=YA.w;  yv[1]=YB.x;  yv[2]=YB.y;  yv[3]=YB.z;  yv[4]=YB.w;
                yv[5]=YC.x;  yv[6]=YC.y;  yv[7]=YC.z;  yv[8]=YC.w;  yv[9]=YD.x;
                yv[10]=YD.y; yv[11]=YD.z; yv[12]=YD.w; yv[13]=YE;
            } else if (rok) {
                const int gc = tx0 + c0;
                const float* prx = xp + (size_t)gy*W_IMG + gc;
                const float* pry = yp + (size_t)gy*W_IMG + gc;
#pragma unroll
                for (int j = 0; j < 14; ++j) {
                    bool ok = (unsigned)(gc + j) < (unsigned)W_IMG;
                    xv[j] = ok ? prx[j] : 0.f;
                    yv[j] = ok ? pry[j] : 0.f;
                }
            } else {
#pragma unroll
                for (int j = 0; j < 14; ++j) { xv[j] = 0.f; yv[j] = 0.f; }
            }

            // fused MSE: only rows OWNED by this block (hr in [0,128)),
            // cols j=5..8 are this task's 4 output columns.
            if ((unsigned)hr < (unsigned)STRIP) {
#pragma unroll
                for (int j = 5; j < 9; ++j) {
                    float d = xv[j] - yv[j];
                    mse_acc = fmaf(d, d, mse_acc);
                }
            }

            // Packed hconv: output-col pairs (2p, 2p+1) in f2 lanes.
            f2 A[5][2];
#pragma unroll
            for (int f = 0; f < 5; ++f) { A[f][0] = splat2(0.f); A[f][1] = splat2(0.f); }
#pragma unroll
            for (int j = 0; j < 14; ++j) {
                float px = xv[j], py = yv[j];
                float pxx = px*px, pyy = py*py, pxy = px*py;
#pragma unroll
                for (int p = 0; p < 2; ++p) {
                    const int t0 = j - 2*p;          // tap for m=2p; m=2p+1 uses t0-1
                    if (t0 >= 0 && t0 <= WS11) {
                        const f2 wp = {WT(t0), WT(t0-1)};
                        A[0][p] = __builtin_elementwise_fma(wp, splat2(px),  A[0][p]);
                        A[1][p] = __builtin_elementwise_fma(wp, splat2(py),  A[1][p]);
                        A[2][p] = __builtin_elementwise_fma(wp, splat2(pxx), A[2][p]);
                        A[3][p] = __builtin_elementwise_fma(wp, splat2(pyy), A[3][p]);
                        A[4][p] = __builtin_elementwise_fma(wp, splat2(pxy), A[4][p]);
                    }
                }
            }
            float* wb = &rbuf[slot*RS + c0];
#pragma unroll
            for (int f = 0; f < 5; ++f) {
                *(float4*)(wb + f*FSTR) =
                    make_float4(A[f][0].x, A[f][0].y, A[f][1].x, A[f][1].y);
            }
        }
        __syncthreads();

        // ---- Stage B: vertical 11-tap + SSIM; ALL 256 threads.
        //      Task = 8 output rows x 1 col; row-pair packed f2 accums
        //      (4 pairs), b32 LDS reads (bank-conflict-free). ----
        {
            const int c  = tid & 31;                   // column
            const int rg = tid >> 5;                   // row group 0..7
            const int sb = (CH*k + (rg << 3)) % RING;  // slot of row y0-5
            f2 acc[5][4];
#pragma unroll
            for (int f = 0; f < 5; ++f)
#pragma unroll
                for (int p = 0; p < 4; ++p) acc[f][p] = splat2(0.f);
            const float* bp = rbuf + c;
#pragma unroll
            for (int i = 0; i < 18; ++i) {
                int sl = sb + i; if (sl >= RING) sl -= RING;
                const float* rp = bp + sl*RS;
#pragma unroll
                for (int f = 0; f < 5; ++f) {
                    float v = rp[f*FSTR];
#pragma unroll
                    for (int p = 0; p < 4; ++p) {
                        const int t0 = i - 2*p;      // tap for row 2p; 2p+1 uses t0-1
                        if (t0 >= 0 && t0 <= WS11) {
                            const f2 wp = {WT(t0), WT(t0-1)};
                            acc[f][p] = __builtin_elementwise_fma(wp, splat2(v), acc[f][p]);
                        }
                    }
                }
            }
            const f2 c1v = {1e-4f, 1e-4f};
            const f2 c2v = {9e-4f, 9e-4f};
            const f2 two2 = {2.f, 2.f};
#pragma unroll
            for (int p = 0; p < 4; ++p) {
                f2 mx = acc[0][p], my = acc[1][p];
                f2 sxx = acc[2][p] - mx*mx;
                f2 syy = acc[3][p] - my*my;
                f2 sxy = acc[4][p] - mx*my;
                f2 num = (two2*mx*my + c1v) * (two2*sxy + c2v);
                f2 den = (mx*mx + my*my + c1v) * (sxx + syy + c2v);
                ssim_acc += __fdividef(num.x, den.x) + __fdividef(num.y, den.y);
            }
        }
        __syncthreads();   // ring rows reused by next chunk / scratch reuse
    }

    // ---- Block reduce (4 waves of 64); reuse rbuf as scratch ----
#pragma unroll
    for (int off = 32; off > 0; off >>= 1) {
        ssim_acc += __shfl_down(ssim_acc, off);
        mse_acc  += __shfl_down(mse_acc, off);
    }
    const int wid = tid >> 6, lane = tid & 63;
    if (lane == 0) { rbuf[wid] = ssim_acc; rbuf[4+wid] = mse_acc; }
    __syncthreads();
    if (tid == 0) {
        part[blockIdx.x] = rbuf[0]+rbuf[1]+rbuf[2]+rbuf[3];
        part[nParts + blockIdx.x] = rbuf[4]+rbuf[5]+rbuf[6]+rbuf[7];
    }
}

// 1024-thread finalize: vectorized partial reduce (double), fast-log BCE,
// curriculum weights.
#define FT 1024
__global__ __launch_bounds__(FT) void finalize_k(
        const float* __restrict__ part, int nParts,
        const float* __restrict__ wm_orig, const float* __restrict__ wm_ext,
        int nWm, const int* __restrict__ epoch_p,
        float* __restrict__ out, double inv_npix, double inv_nwm) {
    __shared__ double red[48];
    int tid = threadIdx.x;
    double s_ssim = 0.0, s_mse = 0.0, s_wl = 0.0;
    const float4* s4 = (const float4*)part;
    const float4* m4 = (const float4*)(part + nParts);
    int n4 = nParts >> 2;
    for (int i = tid; i < n4; i += FT) {
        float4 v = s4[i];
        s_ssim += (double)((v.x + v.y) + (v.z + v.w));
        float4 u = m4[i];
        s_mse  += (double)((u.x + u.y) + (u.z + u.w));
    }
    const float4* p4 = (const float4*)wm_orig;
    const float4* q4 = (const float4*)wm_ext;
    int w4 = nWm >> 2;
    for (int i = tid; i < w4; i += FT) {
        float4 p = p4[i], q = q4[i];
        float a;
        a  = -(p.x*__logf(q.x) + (1.f-p.x)*__logf(1.f-q.x));
        a += -(p.y*__logf(q.y) + (1.f-p.y)*__logf(1.f-q.y));
        a += -(p.z*__logf(q.z) + (1.f-p.z)*__logf(1.f-q.z));
        a += -(p.w*__logf(q.w) + (1.f-p.w)*__logf(1.f-q.w));
        s_wl += (double)a;
    }
#pragma unroll
    for (int off = 32; off > 0; off >>= 1) {
        s_ssim += __shfl_down(s_ssim, off);
        s_mse  += __shfl_down(s_mse, off);
        s_wl   += __shfl_down(s_wl, off);
    }
    int wid = tid >> 6, lane = tid & 63;
    if (lane == 0) { red[wid] = s_ssim; red[16+wid] = s_mse; red[32+wid] = s_wl; }
    __syncthreads();
    if (tid == 0) {
        double ssim_sum = 0.0, mse_sum = 0.0, wl_sum = 0.0;
        for (int i = 0; i < 16; ++i) {
            ssim_sum += red[i]; mse_sum += red[16+i]; wl_sum += red[32+i];
        }
        float sv = (float)(ssim_sum * inv_npix);
        float ml = (float)(mse_sum  * inv_npix);
        float wl = (float)(wl_sum   * inv_nwm);
        int e = *epoch_p;
        float w_img, w_ssim;
        if (e <= 12) {
            w_img = 0.05f; w_ssim = 0.05f;
        } else {
            float progress = fminf(1.0f, (float)(e - 12) / 10.0f);
            w_img  = 0.05f + (0.5f - 0.05f)*progress;
            w_ssim = 0.05f + (0.8f - 0.05f)*progress;
        }
        float sl = 1.0f - sv;
        float total = w_img*ml + w_ssim*sl + 3.0f*wl;
        out[0] = total;
        out[1] = ml;
        out[2] = sv;
        out[3] = wl;
    }
}

extern "C" void kernel_launch(void* const* d_in, const int* in_sizes, int n_in,
                              void* d_out, int out_size, void* d_ws, size_t ws_size,
                              hipStream_t stream) {
    const float* cover   = (const float*)d_in[0];
    const float* wmed    = (const float*)d_in[1];
    const float* wm_orig = (const float*)d_in[2];
    const float* wm_ext  = (const float*)d_in[3];
    const int*   epoch   = (const int*)d_in[4];
    float* out = (float*)d_out;

    int npix   = in_sizes[0];                 // 12,582,912
    int planes = npix / (H_IMG * W_IMG);      // 48
    int nWm    = in_sizes[2];                 // 16,384

    int nBlocks = 16 * 4 * planes;            // 3072 column-strip blocks
    int nParts  = nBlocks;
    float* part = (float*)d_ws;               // 2 * nParts floats (24 KB)

    ssim_mse_tile<<<nBlocks, NTHREADS, 0, stream>>>(cover, wmed, part, nParts);
    finalize_k<<<1, FT, 0, stream>>>(part, nParts, wm_orig, wm_ext, nWm,
                                     epoch, out,
                                     1.0 / (double)npix, 1.0 / (double)nWm);
}

// Round 6
// 178.590 us; speedup vs baseline: 2.9945x; 1.0188x over previous
//
#include <hip/hip_runtime.h>
#include <math.h>

// Problem constants (B=16, C=3 -> 48 planes of 512x512)
#define H_IMG 512
#define W_IMG 512
#define TW 32              // strip width (output cols per block)
#define CH 32              // output rows per chunk
#define NCHUNK 4           // chunks per block -> 128 output rows per block
#define STRIP (CH*NCHUNK)  // 128
#define HALO 5
#define WS11 11
#define RING 42            // ring rows: live window is 42 (32 new + 10 reused)
#define RS 36              // row stride in floats (32 cols + pad, 16B-aligned rows)
#define FSTR (RING*RS)     // 1512 floats per field
#define NTHREADS 256

typedef float f2 __attribute__((ext_vector_type(2)));

// lgkmcnt-only barrier: orders LDS writes/reads across waves WITHOUT
// draining vmcnt, so the L2-warming global loads stay in flight.
// (__syncthreads emits s_waitcnt vmcnt(0) and would stall on them here.)
#define BAR() do { \
    asm volatile("s_waitcnt lgkmcnt(0)" ::: "memory"); \
    __builtin_amdgcn_s_barrier(); \
} while (0)

// Gaussian 11-tap, sigma=1.5, normalized; folds to literals after unroll.
// Out-of-range taps -> 0 so packed pairs can run harmlessly.
__host__ __device__ constexpr float WT(int t) {
    return (t==0||t==10) ? 0.00102838f :
           (t==1||t==9)  ? 0.00759873f :
           (t==2||t==8)  ? 0.03600075f :
           (t==3||t==7)  ? 0.10936070f :
           (t==4||t==6)  ? 0.21300556f :
           (t==5)        ? 0.26601172f : 0.0f;
}

static __device__ __forceinline__ f2 splat2(float v) { f2 r = {v, v}; return r; }

// Column-strip kernel: block = 32 cols x 128 rows of one plane.
// Hconv rows (5 fields) live in a 42-row LDS ring; each image row is
// hconv'd once per block. Per chunk, <=1 warm dword/thread touches every
// 64B line of chunk k+1's rows: issued AFTER Stage A's loads (vmcnt is
// FIFO), carried across an lgkmcnt-only barrier, waited after Stage B
// (~800cy cover) -> next chunk's Stage A loads hit L2 instead of HBM.
__global__ __launch_bounds__(NTHREADS, 4) void ssim_mse_tile(
        const float* __restrict__ cover, const float* __restrict__ wmed,
        float* __restrict__ part, int nParts) {
    __shared__ __align__(16) float rbuf[5*FSTR];   // 30240 B

    const int tid = threadIdx.x;
    const int bx  = blockIdx.x & 15;          // x-strip
    const int ys  = (blockIdx.x >> 4) & 3;    // y quarter
    const int pl  = blockIdx.x >> 6;          // plane
    const size_t pbase = (size_t)pl * (H_IMG*W_IMG);
    const float* xp = wmed + pbase;           // x = wmed, y = cover
    const float* yp = cover + pbase;
    const int Y0  = ys << 7;                  // 0,128,256,384
    const int tx0 = bx*TW - HALO;
    const bool xin = (bx != 0) && (bx != 15); // fast-path columns

    float ssim_acc = 0.f, mse_acc = 0.f;

    for (int k = 0; k < NCHUNK; ++k) {
        // ---- Stage A: hconv the NEW rows of this chunk into the ring ----
        // chunk 0: hr in [-5, 37) (42 rows); chunk k>0: hr in [32k+5, 32k+37)
        const int nrows = (k == 0) ? (CH + 2*HALO) : CH;
        const int hr0   = (k == 0) ? -HALO : (CH*k + HALO);
        const int ntask = nrows << 3;          // 8 col-groups of 4
        float wv = 0.f;                        // warm-load keep-alive value

        for (int t = tid; t < ntask; t += NTHREADS) {
            const int r  = t >> 3, c0 = (t & 7) << 2;
            const int hr = hr0 + r;                  // strip-relative row
            const int gy = Y0 + hr;                  // global row
            const int slot = (hr + HALO) % RING;     // ring slot (>=0)
            const bool rok = (unsigned)gy < (unsigned)H_IMG;
            float xv[14], yv[14];
            if (rok && xin) {
                // ga = bx*32 + c0 - 8 : 16B-aligned, in [24, 484]
                const int ga = tx0 + c0 - 3;
                const float* rx = xp + (size_t)gy*W_IMG + ga;
                const float* ry = yp + (size_t)gy*W_IMG + ga;
                float4 XA = *(const float4*)(rx);
                float4 XB = *(const float4*)(rx + 4);
                float4 XC = *(const float4*)(rx + 8);
                float4 XD = *(const float4*)(rx + 12);
                float  XE = rx[16];
                float4 YA = *(const float4*)(ry);
                float4 YB = *(const float4*)(ry + 4);
                float4 YC = *(const float4*)(ry + 8);
                float4 YD = *(const float4*)(ry + 12);
                float  YE = ry[16];
                xv[0]=XA.w;  xv[1]=XB.x;  xv[2]=XB.y;  xv[3]=XB.z;  xv[4]=XB.w;
                xv[5]=XC.x;  xv[6]=XC.y;  xv[7]=XC.z;  xv[8]=XC.w;  xv[9]=XD.x;
                xv[10]=XD.y; xv[11]=XD.z; xv[12]=XD.w; xv[13]=XE;
                yv[0]=YA.w;  yv[1]=YB.x;  yv[2]=YB.y;  yv[3]=YB.z;  yv[4]=YB.w;
                yv[5]=YC.x;  yv[6]=YC.y;  yv[7]=YC.z;  yv[8]=YC.w;  yv[9]=YD.x;
                yv[10]=YD.y; yv[11]=YD.z; yv[12]=YD.w; yv[13]=YE;
            } else if (rok) {
                const int gc = tx0 + c0;
                const float* prx = xp + (size_t)gy*W_IMG + gc;
                const float* pry = yp + (size_t)gy*W_IMG + gc;
#pragma unroll
                for (int j = 0; j < 14; ++j) {
                    bool ok = (unsigned)(gc + j) < (unsigned)W_IMG;
                    xv[j] = ok ? prx[j] : 0.f;
                    yv[j] = ok ? pry[j] : 0.f;
                }
            } else {
#pragma unroll
                for (int j = 0; j < 14; ++j) { xv[j] = 0.f; yv[j] = 0.f; }
            }

            // ---- L2-warm prefetch of chunk k+1 (first loop iter only).
            // Issued AFTER this task's loads (vmcnt FIFO: consuming those
            // leaves this one in flight), pinned by sched_barriers so the
            // compiler can neither hoist nor sink it. 192 probes cover
            // 32 rows x {x,y} x 3x64B segments. Waited after Stage B.
            if (k + 1 < NCHUNK && t < NTHREADS) {
                __builtin_amdgcn_sched_barrier(0);
                const int rw  = tid >> 3;                 // 0..31
                int sub = tid & 7; if (sub > 5) sub -= 6; // 0..5
                const int arr = (sub >= 3) ? 1 : 0;
                const int seg = sub - (arr ? 3 : 0);      // 0..2
                int gyw = Y0 + CH*(k+1) + HALO + rw;
                if (gyw > H_IMG-1) gyw = H_IMG-1;
                int fc = bx*TW - 8 + (seg << 4);          // 16 floats = 64B
                if (fc < 0) fc = 0;
                if (fc > W_IMG-16) fc = W_IMG-16;
                const float* wp_ = (arr ? yp : xp) + (size_t)gyw*W_IMG + fc;
                wv = *wp_;
                __builtin_amdgcn_sched_barrier(0);
            }

            // fused MSE: only rows OWNED by this block (hr in [0,128)),
            // cols j=5..8 are this task's 4 output columns.
            if ((unsigned)hr < (unsigned)STRIP) {
#pragma unroll
                for (int j = 5; j < 9; ++j) {
                    float d = xv[j] - yv[j];
                    mse_acc = fmaf(d, d, mse_acc);
                }
            }

            // Packed hconv: output-col pairs (2p, 2p+1) in f2 lanes.
            f2 A[5][2];
#pragma unroll
            for (int f = 0; f < 5; ++f) { A[f][0] = splat2(0.f); A[f][1] = splat2(0.f); }
#pragma unroll
            for (int j = 0; j < 14; ++j) {
                float px = xv[j], py = yv[j];
                float pxx = px*px, pyy = py*py, pxy = px*py;
#pragma unroll
                for (int p = 0; p < 2; ++p) {
                    const int t0 = j - 2*p;          // tap for m=2p; m=2p+1 uses t0-1
                    if (t0 >= 0 && t0 <= WS11) {
                        const f2 wp = {WT(t0), WT(t0-1)};
                        A[0][p] = __builtin_elementwise_fma(wp, splat2(px),  A[0][p]);
                        A[1][p] = __builtin_elementwise_fma(wp, splat2(py),  A[1][p]);
                        A[2][p] = __builtin_elementwise_fma(wp, splat2(pxx), A[2][p]);
                        A[3][p] = __builtin_elementwise_fma(wp, splat2(pyy), A[3][p]);
                        A[4][p] = __builtin_elementwise_fma(wp, splat2(pxy), A[4][p]);
                    }
                }
            }
            float* wb = &rbuf[slot*RS + c0];
#pragma unroll
            for (int f = 0; f < 5; ++f) {
                *(float4*)(wb + f*FSTR) =
                    make_float4(A[f][0].x, A[f][0].y, A[f][1].x, A[f][1].y);
            }
        }
        BAR();   // lgkmcnt-only: ring writes visible; warm loads in flight

        // ---- Stage B: vertical 11-tap + SSIM; ALL 256 threads.
        //      Task = 4 output rows x 1 col; row-pair packed f2 accums,
        //      b32 LDS reads (bank-conflict-free, measured 0). ----
        {
            const int c  = tid & 31;             // column
            const int rg = tid >> 5;             // row group 0..7
            const int sb = (CH*k + (rg << 2)) % RING;  // slot of row y0-5
            f2 acc[5][2];
#pragma unroll
            for (int f = 0; f < 5; ++f) {
                acc[f][0] = splat2(0.f); acc[f][1] = splat2(0.f);
            }
            const float* bp = rbuf + c;
#pragma unroll
            for (int i = 0; i < 14; ++i) {
                int sl = sb + i; if (sl >= RING) sl -= RING;
                const float* rp = bp + sl*RS;
#pragma unroll
                for (int f = 0; f < 5; ++f) {
                    float v = rp[f*FSTR];
#pragma unroll
                    for (int p = 0; p < 2; ++p) {
                        const int t0 = i - 2*p;      // tap for row 2p; 2p+1 uses t0-1
                        if (t0 >= 0 && t0 <= WS11) {
                            const f2 wp = {WT(t0), WT(t0-1)};
                            acc[f][p] = __builtin_elementwise_fma(wp, splat2(v), acc[f][p]);
                        }
                    }
                }
            }
            const f2 c1v = {1e-4f, 1e-4f};
            const f2 c2v = {9e-4f, 9e-4f};
            const f2 two2 = {2.f, 2.f};
#pragma unroll
            for (int p = 0; p < 2; ++p) {
                f2 mx = acc[0][p], my = acc[1][p];
                f2 sxx = acc[2][p] - mx*mx;
                f2 syy = acc[3][p] - my*my;
                f2 sxy = acc[4][p] - mx*my;
                f2 num = (two2*mx*my + c1v) * (two2*sxy + c2v);
                f2 den = (mx*mx + my*my + c1v) * (sxx + syy + c2v);
                ssim_acc += __fdividef(num.x, den.x) + __fdividef(num.y, den.y);
            }
        }
        // Keep the warm value alive; forces its vmcnt wait HERE (covered
        // by Stage A + Stage B compute), not inside Stage A.
        asm volatile("" : : "v"(wv));
        __syncthreads();   // ring rows reused by next chunk
    }

    // ---- Block reduce (4 waves of 64); reuse rbuf as scratch ----
#pragma unroll
    for (int off = 32; off > 0; off >>= 1) {
        ssim_acc += __shfl_down(ssim_acc, off);
        mse_acc  += __shfl_down(mse_acc, off);
    }
    const int wid = tid >> 6, lane = tid & 63;
    if (lane == 0) { rbuf[wid] = ssim_acc; rbuf[4+wid] = mse_acc; }
    __syncthreads();
    if (tid == 0) {
        part[blockIdx.x] = rbuf[0]+rbuf[1]+rbuf[2]+rbuf[3];
        part[nParts + blockIdx.x] = rbuf[4]+rbuf[5]+rbuf[6]+rbuf[7];
    }
}

// 1024-thread finalize: vectorized partial reduce (double), fast-log BCE,
// curriculum weights.
#define FT 1024
__global__ __launch_bounds__(FT) void finalize_k(
        const float* __restrict__ part, int nParts,
        const float* __restrict__ wm_orig, const float* __restrict__ wm_ext,
        int nWm, const int* __restrict__ epoch_p,
        float* __restrict__ out, double inv_npix, double inv_nwm) {
    __shared__ double red[48];
    int tid = threadIdx.x;
    double s_ssim = 0.0, s_mse = 0.0, s_wl = 0.0;
    const float4* s4 = (const float4*)part;
    const float4* m4 = (const float4*)(part + nParts);
    int n4 = nParts >> 2;
    for (int i = tid; i < n4; i += FT) {
        float4 v = s4[i];
        s_ssim += (double)((v.x + v.y) + (v.z + v.w));
        float4 u = m4[i];
        s_mse  += (double)((u.x + u.y) + (u.z + u.w));
    }
    const float4* p4 = (const float4*)wm_orig;
    const float4* q4 = (const float4*)wm_ext;
    int w4 = nWm >> 2;
    for (int i = tid; i < w4; i += FT) {
        float4 p = p4[i], q = q4[i];
        float a;
        a  = -(p.x*__logf(q.x) + (1.f-p.x)*__logf(1.f-q.x));
        a += -(p.y*__logf(q.y) + (1.f-p.y)*__logf(1.f-q.y));
        a += -(p.z*__logf(q.z) + (1.f-p.z)*__logf(1.f-q.z));
        a += -(p.w*__logf(q.w) + (1.f-p.w)*__logf(1.f-q.w));
        s_wl += (double)a;
    }
#pragma unroll
    for (int off = 32; off > 0; off >>= 1) {
        s_ssim += __shfl_down(s_ssim, off);
        s_mse  += __shfl_down(s_mse, off);
        s_wl   += __shfl_down(s_wl, off);
    }
    int wid = tid >> 6, lane = tid & 63;
    if (lane == 0) { red[wid] = s_ssim; red[16+wid] = s_mse; red[32+wid] = s_wl; }
    __syncthreads();
    if (tid == 0) {
        double ssim_sum = 0.0, mse_sum = 0.0, wl_sum = 0.0;
        for (int i = 0; i < 16; ++i) {
            ssim_sum += red[i]; mse_sum += red[16+i]; wl_sum += red[32+i];
        }
        float sv = (float)(ssim_sum * inv_npix);
        float ml = (float)(mse_sum  * inv_npix);
        float wl = (float)(wl_sum   * inv_nwm);
        int e = *epoch_p;
        float w_img, w_ssim;
        if (e <= 12) {
            w_img = 0.05f; w_ssim = 0.05f;
        } else {
            float progress = fminf(1.0f, (float)(e - 12) / 10.0f);
            w_img  = 0.05f + (0.5f - 0.05f)*progress;
            w_ssim = 0.05f + (0.8f - 0.05f)*progress;
        }
        float sl = 1.0f - sv;
        float total = w_img*ml + w_ssim*sl + 3.0f*wl;
        out[0] = total;
        out[1] = ml;
        out[2] = sv;
        out[3] = wl;
    }
}

extern "C" void kernel_launch(void* const* d_in, const int* in_sizes, int n_in,
                              void* d_out, int out_size, void* d_ws, size_t ws_size,
                              hipStream_t stream) {
    const float* cover   = (const float*)d_in[0];
    const float* wmed    = (const float*)d_in[1];
    const float* wm_orig = (const float*)d_in[2];
    const float* wm_ext  = (const float*)d_in[3];
    const int*   epoch   = (const int*)d_in[4];
    float* out = (float*)d_out;

    int npix   = in_sizes[0];                 // 12,582,912
    int planes = npix / (H_IMG * W_IMG);      // 48
    int nWm    = in_sizes[2];                 // 16,384

    int nBlocks = 16 * 4 * planes;            // 3072 column-strip blocks
    int nParts  = nBlocks;
    float* part = (float*)d_ws;               // 2 * nParts floats (24 KB)

    ssim_mse_tile<<<nBlocks, NTHREADS, 0, stream>>>(cover, wmed, part, nParts);
    finalize_k<<<1, FT, 0, stream>>>(part, nParts, wm_orig, wm_ext, nWm,
                                     epoch, out,
                                     1.0 / (double)npix, 1.0 / (double)nWm);
}

// Round 7
// 173.657 us; speedup vs baseline: 3.0796x; 1.0284x over previous
//
#include <hip/hip_runtime.h>
#include <math.h>

// Problem constants (B=16, C=3 -> 48 planes of 512x512)
#define H_IMG 512
#define W_IMG 512
#define TW 32              // strip width (output cols per wave)
#define STRIP 128          // output rows per wave strip
#define HALO 5
#define WS11 11
#define RING 18            // per-wave ring rows: 8 new + 10 halo
#define RS 36              // row stride in floats (32 cols + pad)
#define FSTR (RING*RS)     // 648 floats per field
#define WLDS (5*FSTR)      // 3240 floats per wave (12960 B)
#define NTHREADS 256

typedef float f2 __attribute__((ext_vector_type(2)));

// Gaussian 11-tap, sigma=1.5, normalized; folds to literals after unroll.
// Out-of-range taps -> 0 so packed pairs can run harmlessly.
__host__ __device__ constexpr float WT(int t) {
    return (t==0||t==10) ? 0.00102838f :
           (t==1||t==9)  ? 0.00759873f :
           (t==2||t==8)  ? 0.03600075f :
           (t==3||t==7)  ? 0.10936070f :
           (t==4||t==6)  ? 0.21300556f :
           (t==5)        ? 0.26601172f : 0.0f;
}

static __device__ __forceinline__ f2 splat2(float v) { f2 r = {v, v}; return r; }

// Wave-autonomous kernel: each WAVE owns a 32-col x 128-row strip with a
// private 18-row hconv ring in its LDS slice. No s_barrier in the main
// loop: intra-wave hconv->vconv ordering is program order + lgkmcnt
// (compiler-inserted). Waves de-phase freely, so one wave's global-load
// stall is covered by the other 11 waves on the CU, and the compiler may
// hoist next-iteration loads above vconv (no vmcnt(0) drain anywhere).
// Per iteration (8 output rows): 64 hconv tasks (1/lane, 8 rows x 8
// col-groups) then 64 vconv tasks (1/lane, 4 rows x 1 col).
// LDS patterns identical to the measured-conflict-free R2 ones.
__global__ __launch_bounds__(NTHREADS, 3) void ssim_mse_tile(
        const float* __restrict__ cover, const float* __restrict__ wmed,
        float* __restrict__ part, int nParts) {
    __shared__ __align__(16) float rbuf[4*WLDS];   // 51840 B -> 3 blocks/CU

    const int tid  = threadIdx.x;
    const int w    = tid >> 6;                // wave 0..3 -> y quarter
    const int lane = tid & 63;
    const int bx   = blockIdx.x & 15;         // x-strip
    const int pl   = blockIdx.x >> 4;         // plane
    const size_t pbase = (size_t)pl * (H_IMG*W_IMG);
    const float* xp = wmed + pbase;           // x = wmed, y = cover
    const float* yp = cover + pbase;
    const int Y0  = w << 7;                   // 0,128,256,384
    const int tx0 = bx*TW - HALO;
    const bool xin = (bx != 0) && (bx != 15); // fast-path columns
    float* ring = &rbuf[w*WLDS];

    const int rL  = lane >> 3;                // hconv row-in-group 0..7
    const int c0  = (lane & 7) << 2;          // hconv col group
    const int cB  = lane & 31;                // vconv column
    const int rgB = lane >> 5;                // vconv row group 0..1

    float ssim_acc = 0.f, mse_acc = 0.f;

    // ================= hconv task body (macro'd via lambda) =============
    auto hconv_task = [&](int hr, int slot, int cc) {
        const int gy = Y0 + hr;
        const bool rok = (unsigned)gy < (unsigned)H_IMG;
        float xv[14], yv[14];
        if (rok && xin) {
            // ga = bx*32 + cc - 8 : 16B-aligned, in [24, 484]
            const int ga = tx0 + cc - 3;
            const float* rx = xp + (size_t)gy*W_IMG + ga;
            const float* ry = yp + (size_t)gy*W_IMG + ga;
            float4 XA = *(const float4*)(rx);
            float4 XB = *(const float4*)(rx + 4);
            float4 XC = *(const float4*)(rx + 8);
            float4 XD = *(const float4*)(rx + 12);
            float  XE = rx[16];
            float4 YA = *(const float4*)(ry);
            float4 YB = *(const float4*)(ry + 4);
            float4 YC = *(const float4*)(ry + 8);
            float4 YD = *(const float4*)(ry + 12);
            float  YE = ry[16];
            xv[0]=XA.w;  xv[1]=XB.x;  xv[2]=XB.y;  xv[3]=XB.z;  xv[4]=XB.w;
            xv[5]=XC.x;  xv[6]=XC.y;  xv[7]=XC.z;  xv[8]=XC.w;  xv[9]=XD.x;
            xv[10]=XD.y; xv[11]=XD.z; xv[12]=XD.w; xv[13]=XE;
            yv[0]=YA.w;  yv[1]=YB.x;  yv[2]=YB.y;  yv[3]=YB.z;  yv[4]=YB.w;
            yv[5]=YC.x;  yv[6]=YC.y;  yv[7]=YC.z;  yv[8]=YC.w;  yv[9]=YD.x;
            yv[10]=YD.y; yv[11]=YD.z; yv[12]=YD.w; yv[13]=YE;
        } else if (rok) {
            const int gc = tx0 + cc;
            const float* prx = xp + (size_t)gy*W_IMG + gc;
            const float* pry = yp + (size_t)gy*W_IMG + gc;
#pragma unroll
            for (int j = 0; j < 14; ++j) {
                bool ok = (unsigned)(gc + j) < (unsigned)W_IMG;
                xv[j] = ok ? prx[j] : 0.f;
                yv[j] = ok ? pry[j] : 0.f;
            }
        } else {
#pragma unroll
            for (int j = 0; j < 14; ++j) { xv[j] = 0.f; yv[j] = 0.f; }
        }

        // fused MSE on owned rows (hr in [0,128)); cols j=5..8 are this
        // task's 4 output columns.
        if ((unsigned)hr < (unsigned)STRIP) {
#pragma unroll
            for (int j = 5; j < 9; ++j) {
                float d = xv[j] - yv[j];
                mse_acc = fmaf(d, d, mse_acc);
            }
        }

        // Packed hconv: output-col pairs (2p, 2p+1) in f2 lanes.
        f2 A[5][2];
#pragma unroll
        for (int f = 0; f < 5; ++f) { A[f][0] = splat2(0.f); A[f][1] = splat2(0.f); }
#pragma unroll
        for (int j = 0; j < 14; ++j) {
            float px = xv[j], py = yv[j];
            float pxx = px*px, pyy = py*py, pxy = px*py;
#pragma unroll
            for (int p = 0; p < 2; ++p) {
                const int t0 = j - 2*p;          // tap for m=2p; m=2p+1 uses t0-1
                if (t0 >= 0 && t0 <= WS11) {
                    const f2 wp = {WT(t0), WT(t0-1)};
                    A[0][p] = __builtin_elementwise_fma(wp, splat2(px),  A[0][p]);
                    A[1][p] = __builtin_elementwise_fma(wp, splat2(py),  A[1][p]);
                    A[2][p] = __builtin_elementwise_fma(wp, splat2(pxx), A[2][p]);
                    A[3][p] = __builtin_elementwise_fma(wp, splat2(pyy), A[3][p]);
                    A[4][p] = __builtin_elementwise_fma(wp, splat2(pxy), A[4][p]);
                }
            }
        }
        float* wb = &ring[slot*RS + cc];
#pragma unroll
        for (int f = 0; f < 5; ++f) {
            *(float4*)(wb + f*FSTR) =
                make_float4(A[f][0].x, A[f][0].y, A[f][1].x, A[f][1].y);
        }
    };

    // ---- Prologue: hconv halo rows hr = -5..4 -> slots 0..9 (80 tasks) ----
    hconv_task((lane >> 3) - HALO, lane >> 3, (lane & 7) << 2);
    if (lane < 16) {
        const int t = lane + 64;
        hconv_task((t >> 3) - HALO, t >> 3, (t & 7) << 2);
    }

    // ---- Main loop: 16 iterations x 8 output rows. NO BARRIERS. ----
    int sA = 10;   // ring slot of hconv row 8k+5  ( = (8k+10) mod 18 )
    int sV = 0;    // ring slot of vconv input row 8k-5 ( = (8k) mod 18 )
    for (int k = 0; k < 16; ++k) {
        // hconv the 8 NEW rows (1 task/lane); program order + lgkmcnt
        // make them visible to this wave's vconv below.
        {
            int slot = sA + rL; if (slot >= RING) slot -= RING;
            hconv_task(8*k + HALO + rL, slot, c0);
        }

        // vconv + SSIM: 4 output rows x 1 col per lane, row-pair packed
        // f2 accumulators, b32 LDS reads (2 row-groups/wave -> 2-way, free).
        {
            int sb = sV + (rgB << 2); if (sb >= RING) sb -= RING;
            f2 acc[5][2];
#pragma unroll
            for (int f = 0; f < 5; ++f) {
                acc[f][0] = splat2(0.f); acc[f][1] = splat2(0.f);
            }
            const float* bp = ring + cB;
#pragma unroll
            for (int i = 0; i < 14; ++i) {
                int sl = sb + i; if (sl >= RING) sl -= RING;
                const float* rp = bp + sl*RS;
#pragma unroll
                for (int f = 0; f < 5; ++f) {
                    float v = rp[f*FSTR];
#pragma unroll
                    for (int p = 0; p < 2; ++p) {
                        const int t0 = i - 2*p;      // tap for row 2p; 2p+1 uses t0-1
                        if (t0 >= 0 && t0 <= WS11) {
                            const f2 wp = {WT(t0), WT(t0-1)};
                            acc[f][p] = __builtin_elementwise_fma(wp, splat2(v), acc[f][p]);
                        }
                    }
                }
            }
            const f2 c1v = {1e-4f, 1e-4f};
            const f2 c2v = {9e-4f, 9e-4f};
            const f2 two2 = {2.f, 2.f};
#pragma unroll
            for (int p = 0; p < 2; ++p) {
                f2 mx = acc[0][p], my = acc[1][p];
                f2 sxx = acc[2][p] - mx*mx;
                f2 syy = acc[3][p] - my*my;
                f2 sxy = acc[4][p] - mx*my;
                f2 num = (two2*mx*my + c1v) * (two2*sxy + c2v);
                f2 den = (mx*mx + my*my + c1v) * (sxx + syy + c2v);
                ssim_acc += __fdividef(num.x, den.x) + __fdividef(num.y, den.y);
            }
        }

        sA += 8; if (sA >= RING) sA -= RING;
        sV += 8; if (sV >= RING) sV -= RING;
    }

    // ---- Reduce: per-wave shuffle, then one cross-wave pass ----
#pragma unroll
    for (int off = 32; off > 0; off >>= 1) {
        ssim_acc += __shfl_down(ssim_acc, off);
        mse_acc  += __shfl_down(mse_acc, off);
    }
    __syncthreads();   // all waves done with their rings before scratch reuse
    if (lane == 0) { rbuf[w] = ssim_acc; rbuf[4+w] = mse_acc; }
    __syncthreads();
    if (tid == 0) {
        part[blockIdx.x] = rbuf[0]+rbuf[1]+rbuf[2]+rbuf[3];
        part[nParts + blockIdx.x] = rbuf[4]+rbuf[5]+rbuf[6]+rbuf[7];
    }
}

// 1024-thread finalize: vectorized partial reduce (double), fast-log BCE,
// curriculum weights.
#define FT 1024
__global__ __launch_bounds__(FT) void finalize_k(
        const float* __restrict__ part, int nParts,
        const float* __restrict__ wm_orig, const float* __restrict__ wm_ext,
        int nWm, const int* __restrict__ epoch_p,
        float* __restrict__ out, double inv_npix, double inv_nwm) {
    __shared__ double red[48];
    int tid = threadIdx.x;
    double s_ssim = 0.0, s_mse = 0.0, s_wl = 0.0;
    const float4* s4 = (const float4*)part;
    const float4* m4 = (const float4*)(part + nParts);
    int n4 = nParts >> 2;
    for (int i = tid; i < n4; i += FT) {
        float4 v = s4[i];
        s_ssim += (double)((v.x + v.y) + (v.z + v.w));
        float4 u = m4[i];
        s_mse  += (double)((u.x + u.y) + (u.z + u.w));
    }
    const float4* p4 = (const float4*)wm_orig;
    const float4* q4 = (const float4*)wm_ext;
    int w4 = nWm >> 2;
    for (int i = tid; i < w4; i += FT) {
        float4 p = p4[i], q = q4[i];
        float a;
        a  = -(p.x*__logf(q.x) + (1.f-p.x)*__logf(1.f-q.x));
        a += -(p.y*__logf(q.y) + (1.f-p.y)*__logf(1.f-q.y));
        a += -(p.z*__logf(q.z) + (1.f-p.z)*__logf(1.f-q.z));
        a += -(p.w*__logf(q.w) + (1.f-p.w)*__logf(1.f-q.w));
        s_wl += (double)a;
    }
#pragma unroll
    for (int off = 32; off > 0; off >>= 1) {
        s_ssim += __shfl_down(s_ssim, off);
        s_mse  += __shfl_down(s_mse, off);
        s_wl   += __shfl_down(s_wl, off);
    }
    int wid = tid >> 6, lane = tid & 63;
    if (lane == 0) { red[wid] = s_ssim; red[16+wid] = s_mse; red[32+wid] = s_wl; }
    __syncthreads();
    if (tid == 0) {
        double ssim_sum = 0.0, mse_sum = 0.0, wl_sum = 0.0;
        for (int i = 0; i < 16; ++i) {
            ssim_sum += red[i]; mse_sum += red[16+i]; wl_sum += red[32+i];
        }
        float sv = (float)(ssim_sum * inv_npix);
        float ml = (float)(mse_sum  * inv_npix);
        float wl = (float)(wl_sum   * inv_nwm);
        int e = *epoch_p;
        float w_img, w_ssim;
        if (e <= 12) {
            w_img = 0.05f; w_ssim = 0.05f;
        } else {
            float progress = fminf(1.0f, (float)(e - 12) / 10.0f);
            w_img  = 0.05f + (0.5f - 0.05f)*progress;
            w_ssim = 0.05f + (0.8f - 0.05f)*progress;
        }
        float sl = 1.0f - sv;
        float total = w_img*ml + w_ssim*sl + 3.0f*wl;
        out[0] = total;
        out[1] = ml;
        out[2] = sv;
        out[3] = wl;
    }
}

extern "C" void kernel_launch(void* const* d_in, const int* in_sizes, int n_in,
                              void* d_out, int out_size, void* d_ws, size_t ws_size,
                              hipStream_t stream) {
    const float* cover   = (const float*)d_in[0];
    const float* wmed    = (const float*)d_in[1];
    const float* wm_orig = (const float*)d_in[2];
    const float* wm_ext  = (const float*)d_in[3];
    const int*   epoch   = (const int*)d_in[4];
    float* out = (float*)d_out;

    int npix   = in_sizes[0];                 // 12,582,912
    int planes = npix / (H_IMG * W_IMG);      // 48
    int nWm    = in_sizes[2];                 // 16,384

    int nBlocks = 16 * planes;                // 768 blocks; 4 wave-strips each
    int nParts  = nBlocks;
    float* part = (float*)d_ws;               // 2 * nParts floats (6 KB)

    ssim_mse_tile<<<nBlocks, NTHREADS, 0, stream>>>(cover, wmed, part, nParts);
    finalize_k<<<1, FT, 0, stream>>>(part, nParts, wm_orig, wm_ext, nWm,
                                     epoch, out,
                                     1.0 / (double)npix, 1.0 / (double)nWm);
}